// Round 3
// baseline (274.090 us; speedup 1.0000x reference)
//
#include <hip/hip_runtime.h>
#include <math.h>

// Problem constants
#define HH 512
#define WW 512
#define NB 64
#define CXY 56          // crop offset of Xc in x
#define TOFF 66         // crop offset of tmpl in template (MS+C = 10+56)
#define TN 380          // template side
#define XN 400          // cropped image side
#define NL 21           // number of lags per dim (XN-TN+1)
#define N_T 144400.0f   // TN*TN
#define EPSF 1e-8f

// d_ws float offsets
#define TPART_S   0                    // 380
#define TPART_S2  384                  // 380
#define TSTATS    768                  // [0]=mu_t [1]=t_var
#define ROWSUM    1024                 // 64*400*21 = 537600
#define ROWSUMSQ  (ROWSUM + 537600)
#define LOCALSUM  (ROWSUMSQ + 537600)  // 64*441
#define LOCALSQ   (LOCALSUM + 28224)
#define CCPART    (LOCALSQ + 28224)    // 64*16*441 = 451584
#define SHIFTS    (CCPART + 451584)    // 128  (final float shifts)
#define SHIFTSI   (SHIFTS + 128)       // 128  (integer argmax cells)

typedef _Float16 half2_t __attribute__((ext_vector_type(2)));

#if defined(__has_builtin)
#if __has_builtin(__builtin_amdgcn_fdot2)
#define FDOT2(a, b, c) __builtin_amdgcn_fdot2((a), (b), (c), false)
#endif
#endif
#ifndef FDOT2
static __device__ inline float fdot2_asm(half2_t a, half2_t b, float c) {
    asm("v_dot2_f32_f16 %0, %1, %2, %0" : "+v"(c) : "v"(a), "v"(b));
    return c;
}
#define FDOT2(a, b, c) fdot2_asm((a), (b), (c))
#endif

static __device__ inline half2_t as_h2(float f) {
    return __builtin_bit_cast(half2_t, f);
}

// ---------------- K0a: per-template-row partial sums ----------------
__global__ __launch_bounds__(128) void k_tstats1(const float* __restrict__ tpl,
                                                 float* __restrict__ ws) {
    int u = blockIdx.x;            // 0..379
    int l = threadIdx.x;           // 128
    const float* row = tpl + (TOFF + u) * WW + TOFF;
    float s = 0.f, s2 = 0.f;
    for (int v = l; v < TN; v += 128) { float t = row[v]; s += t; s2 += t * t; }
    for (int off = 32; off; off >>= 1) { s += __shfl_down(s, off); s2 += __shfl_down(s2, off); }
    __shared__ float rs[2], rs2[2];
    int wid = l >> 6;
    if ((l & 63) == 0) { rs[wid] = s; rs2[wid] = s2; }
    __syncthreads();
    if (l == 0) { ws[TPART_S + u] = rs[0] + rs[1]; ws[TPART_S2 + u] = rs2[0] + rs2[1]; }
}

// ---------------- K0b: finalize template stats ----------------
__global__ __launch_bounds__(512) void k_tstats2(float* __restrict__ ws) {
    int l = threadIdx.x;           // 512
    float s  = (l < TN) ? ws[TPART_S + l]  : 0.f;
    float s2 = (l < TN) ? ws[TPART_S2 + l] : 0.f;
    for (int off = 32; off; off >>= 1) { s += __shfl_down(s, off); s2 += __shfl_down(s2, off); }
    __shared__ float rs[8], rs2[8];
    int wid = l >> 6;
    if ((l & 63) == 0) { rs[wid] = s; rs2[wid] = s2; }
    __syncthreads();
    if (l == 0) {
        float S = 0.f, S2 = 0.f;
        for (int k = 0; k < 8; ++k) { S += rs[k]; S2 += rs2[k]; }
        float mu = S / N_T;
        ws[TSTATS] = mu;
        ws[TSTATS + 1] = S2 - S * mu + EPSF;   // sum((T-mu)^2) + EPS
    }
}

// ---------------- K1: per-row 380-wide sliding window sums ----------------
__global__ __launch_bounds__(256) void k_rowsum(const float* __restrict__ x,
                                                float* __restrict__ ws) {
    __shared__ float sm[4][XN];
    int wid = threadIdx.x >> 6, lane = threadIdx.x & 63;
    int row = blockIdx.x * 4 + wid;        // 0..25599
    int b = row / XN, p = row % XN;
    const float* xr = x + ((size_t)b * HH + (CXY + p)) * WW + CXY;
    float s = 0.f, s2 = 0.f;
    for (int v = lane; v < XN; v += 64) {
        float t = xr[v];
        sm[wid][v] = t;
        if (v < TN) { s += t; s2 += t * t; }
    }
    for (int off = 32; off; off >>= 1) { s += __shfl_down(s, off); s2 += __shfl_down(s2, off); }
    __syncthreads();
    if (lane == 0) {
        float* rs  = ws + ROWSUM   + (size_t)row * NL;
        float* rq  = ws + ROWSUMSQ + (size_t)row * NL;
        float w = s, w2 = s2;
        rs[0] = w; rq[0] = w2;
        for (int j = 1; j < NL; ++j) {
            float a = sm[wid][j - 1], bv = sm[wid][j + TN - 1];
            w  += bv - a;
            w2 += bv * bv - a * a;
            rs[j] = w; rq[j] = w2;
        }
    }
}

// ---------------- K2: vertical 380-tall sums -> localsum / localsum_sq ----------------
__global__ __launch_bounds__(512) void k_vert(float* __restrict__ ws) {
    int b = blockIdx.x, t = threadIdx.x;
    __shared__ float sm[XN * NL];   // 8400 floats = 33.6KB
    for (int k = t; k < XN * NL; k += 512) sm[k] = ws[ROWSUM + (size_t)b * (XN * NL) + k];
    __syncthreads();
    if (t < NL * NL) {
        float s = 0.f;
        for (int p = 0; p < TN; ++p) s += sm[t + p * NL];
        ws[LOCALSUM + b * (NL * NL) + t] = s;
    }
    __syncthreads();
    for (int k = t; k < XN * NL; k += 512) sm[k] = ws[ROWSUMSQ + (size_t)b * (XN * NL) + k];
    __syncthreads();
    if (t < NL * NL) {
        float s = 0.f;
        for (int p = 0; p < TN; ++p) s += sm[t + p * NL];
        ws[LOCALSQ + b * (NL * NL) + t] = s;
    }
}

// ---------------- K3: f16 cross-correlation via v_dot2_f32_f16 ----------------
// acc[j] += X[v+j]*T[v] done as dot2 pairs over v. Pairs (X[m],X[m+1]) come from
// sXa (even m, aligned) or sXb (odd m; sXb[k]=X[k+1]). T rows staged as f16 ring.
#define RPB 25           // X rows per block (16 blocks/batch)
#define TSH 388          // halfs per T row in LDS (194 floats; 776 B row stride)
__global__ __launch_bounds__(256) void k_cc(const float* __restrict__ x,
                                            const float* __restrict__ tpl,
                                            float* __restrict__ ws) {
    __shared__ __align__(16) float sThF[21 * 194];   // 21 T rows as f16
    __shared__ __align__(16) float sXaF[208];        // 416 halfs
    __shared__ __align__(16) float sXbF[208];        // 416 halfs (shifted by 1)
    _Float16* sTh = (_Float16*)sThF;
    _Float16* sXa = (_Float16*)sXaF;
    _Float16* sXb = (_Float16*)sXbF;
    const int b = blockIdx.x, s = blockIdx.y;
    const int p0 = s * RPB;
    const int tid = threadIdx.x;
    const float mu = ws[TSTATS];

    // initial ring: T rows u in [p0-20, p0-1]
    for (int r = 0; r < 20; ++r) {
        int u = p0 - 20 + r;
        int slot = ((u % 21) + 21) % 21;
        _Float16* dst = sTh + slot * TSH;
        if (u >= 0) {
            const float* src = tpl + (TOFF + u) * WW + TOFF;
            for (int w = tid; w < TSH; w += 256) dst[w] = (_Float16)((w < TN) ? (src[w] - mu) : 0.f);
        } else {
            for (int w = tid; w < TSH; w += 256) dst[w] = (_Float16)0.f;
        }
    }

    const int i = tid % 21, c = tid / 21;   // lag-row, v-chunk(32); active if tid<252
    const bool act = (tid < 252);
    float acc[NL];
#pragma unroll
    for (int j = 0; j < NL; ++j) acc[j] = 0.f;

    // prefetch row p0 (raw f32; convert at LDS-write time)
    float tp0 = 0.f, tp1 = 0.f, xp0 = 0.f, xp1 = 0.f;
    {
        if (p0 < TN) {
            const float* src = tpl + (TOFF + p0) * WW + TOFF;
            tp0 = src[tid]; tp1 = src[tid + 256];    // in-bounds: TOFF+387 < 512
        }
        const float* xr = x + ((size_t)b * HH + (CXY + p0)) * WW + CXY;
        xp0 = xr[tid]; xp1 = xr[tid + 256];          // in-bounds: CXY+407 < 512
    }

    for (int p = p0; p < p0 + RPB; ++p) {
        __syncthreads();   // full drain: prev compute done + prefetch loads arrived
        if (p <= TN - 1) { // stage template row u=p into slot p%21
            _Float16* dst = sTh + (p % 21) * TSH;
            dst[tid] = (_Float16)(tp0 - mu);
            if (tid + 256 < TSH) dst[tid + 256] = (_Float16)((tid + 256 < TN) ? (tp1 - mu) : 0.f);
        }
        {   // stage X row p into sXa (aligned) and sXb (shift-1)
            float xa0 = (tid < XN) ? xp0 : 0.f;
            float xa1 = (tid + 256 < XN) ? xp1 : 0.f;
            _Float16 h0 = (_Float16)xa0, h1 = (_Float16)xa1;
            sXa[tid] = h0;
            if (tid + 256 < 416) sXa[tid + 256] = h1;
            if (tid >= 1) sXb[tid - 1] = h0;
            if (tid + 255 < 416) sXb[tid + 255] = h1;
        }
        // prefetch row p+1 (overlaps compute; not drained at the raw barrier)
        {
            int pn = p + 1;
            if (pn < TN) {
                const float* src = tpl + (TOFF + pn) * WW + TOFF;
                tp0 = src[tid]; tp1 = src[tid + 256];
            }
            if (pn < XN) {
                const float* xr = x + ((size_t)b * HH + (CXY + pn)) * WW + CXY;
                xp0 = xr[tid]; xp1 = xr[tid + 256];
            }
        }
        // raw barrier: waits LDS writes only; prefetch vmem stays in flight
        asm volatile("s_waitcnt lgkmcnt(0)\n\ts_barrier" ::: "memory");

        int u = p - i;
        if (act && u <= TN - 1) {           // u<0 slots are zero-filled: contribute 0
            int slot = ((u % 21) + 21) % 21;
            // T chunk: 32 halfs = 16 half2, via 8 x ds_read_b64
            const float2* trow = (const float2*)sThF + slot * 97 + c * 8;
            half2_t t2[16];
#pragma unroll
            for (int k = 0; k < 8; ++k) {
                float2 f2 = trow[k];
                t2[2 * k]     = as_h2(f2.x);
                t2[2 * k + 1] = as_h2(f2.y);
            }
            // X windows: 28 half2 each from sXa/sXb via 7 x ds_read_b128
            const float4* wa4 = (const float4*)sXaF + 4 * c;
            const float4* wb4 = (const float4*)sXbF + 4 * c;
            half2_t wA[28], wB[28];
#pragma unroll
            for (int q = 0; q < 7; ++q) {
                float4 va = wa4[q];
                wA[4 * q]     = as_h2(va.x); wA[4 * q + 1] = as_h2(va.y);
                wA[4 * q + 2] = as_h2(va.z); wA[4 * q + 3] = as_h2(va.w);
                float4 vb = wb4[q];
                wB[4 * q]     = as_h2(vb.x); wB[4 * q + 1] = as_h2(vb.y);
                wB[4 * q + 2] = as_h2(vb.z); wB[4 * q + 3] = as_h2(vb.w);
            }
#pragma unroll
            for (int v2 = 0; v2 < 16; ++v2) {
                half2_t t = t2[v2];
#pragma unroll
                for (int j = 0; j < NL; ++j) {
                    half2_t xp = (j & 1) ? wB[v2 + ((j - 1) >> 1)] : wA[v2 + (j >> 1)];
                    acc[j] = FDOT2(xp, t, acc[j]);
                }
            }
        }
    }

    // two-pass deterministic reduction over c-chunks (reuse sThF: need 2772 floats)
    float* red = sThF;
    __syncthreads();
    if (act && i < 11) {
#pragma unroll
        for (int j = 0; j < NL; ++j) red[(i * NL + j) * 12 + c] = acc[j];
    }
    __syncthreads();
    if (tid < 231) {
        float ssum = 0.f;
#pragma unroll
        for (int cc2 = 0; cc2 < 12; ++cc2) ssum += red[tid * 12 + cc2];
        ws[CCPART + ((size_t)(b * 16 + s)) * (NL * NL) + tid] = ssum;
    }
    __syncthreads();
    if (act && i >= 11) {
#pragma unroll
        for (int j = 0; j < NL; ++j) red[((i - 11) * NL + j) * 12 + c] = acc[j];
    }
    __syncthreads();
    if (tid < 210) {
        float ssum = 0.f;
#pragma unroll
        for (int cc2 = 0; cc2 < 12; ++cc2) ssum += red[tid * 12 + cc2];
        ws[CCPART + ((size_t)(b * 16 + s)) * (NL * NL) + 231 + tid] = ssum;
    }
}

// ---------------- K4: NCC + argmax (first-index ties) -> integer cell ----------------
__global__ __launch_bounds__(512) void k_ncc(float* __restrict__ ws) {
    int b = blockIdx.x, t = threadIdx.x;
    __shared__ float vbuf[512];
    __shared__ int   ibuf[512];
    float val = -1e30f;
    if (t < NL * NL) {
        float num = 0.f;
        for (int sl = 0; sl < 16; ++sl)
            num += ws[CCPART + ((size_t)(b * 16 + sl)) * (NL * NL) + t];
        float ls  = ws[LOCALSUM + b * (NL * NL) + t];
        float lsq = ws[LOCALSQ  + b * (NL * NL) + t];
        float ivar = lsq - ls * ls * (1.0f / N_T) + EPSF;
        if (ivar < 0.f) ivar = 0.f;
        float den = sqrtf(ws[TSTATS + 1] * ivar);
        float ncc = num / den;
        if (ncc != ncc) ncc = 0.f;
        val = ncc;
    }
    vbuf[t] = val; ibuf[t] = t;
    __syncthreads();
    for (int off = 256; off; off >>= 1) {
        if (t < off) {
            float v1 = vbuf[t], v2 = vbuf[t + off];
            int   i1 = ibuf[t], i2 = ibuf[t + off];
            if (v2 > v1 || (v2 == v1 && i2 < i1)) { vbuf[t] = v2; ibuf[t] = i2; }
        }
        __syncthreads();
    }
    if (t == 0) {
        int am = ibuf[0];
        ws[SHIFTSI + 2 * b]     = (float)(am / NL);
        ws[SHIFTSI + 2 * b + 1] = (float)(am % NL);
    }
}

// ---------------- K4b: exact fp32 NCC at the 5 stencil points + subpixel ----------------
__global__ __launch_bounds__(384) void k_exact(const float* __restrict__ x,
                                               const float* __restrict__ tpl,
                                               float* __restrict__ ws) {
    int b = blockIdx.x, t = threadIdx.x;
    int sx = (int)ws[SHIFTSI + 2 * b];
    int sy = (int)ws[SHIFTSI + 2 * b + 1];
    int lxm = max(sx - 1, 0), lxp = min(sx + 1, NL - 1);
    int lym = max(sy - 1, 0), lyp = min(sy + 1, NL - 1);
    float mu = ws[TSTATS], tvar = ws[TSTATS + 1];
    float a0 = 0.f, a1 = 0.f, a2 = 0.f, a3 = 0.f, a4 = 0.f;
    if (t < TN) {
        const float* trow = tpl + (TOFF + t) * WW + TOFF;
        const float* r0 = x + ((size_t)b * HH + (CXY + sx  + t)) * WW + CXY;
        const float* r1 = x + ((size_t)b * HH + (CXY + lxm + t)) * WW + CXY;
        const float* r2 = x + ((size_t)b * HH + (CXY + lxp + t)) * WW + CXY;
#pragma unroll 4
        for (int v = 0; v < TN; ++v) {
            float tz = trow[v] - mu;
            a0 = fmaf(tz, r0[sy + v],  a0);
            a1 = fmaf(tz, r1[sy + v],  a1);
            a2 = fmaf(tz, r2[sy + v],  a2);
            a3 = fmaf(tz, r0[lym + v], a3);
            a4 = fmaf(tz, r0[lyp + v], a4);
        }
    }
    for (int off = 32; off; off >>= 1) {
        a0 += __shfl_down(a0, off); a1 += __shfl_down(a1, off);
        a2 += __shfl_down(a2, off); a3 += __shfl_down(a3, off);
        a4 += __shfl_down(a4, off);
    }
    __shared__ float rbuf[5][6];
    int wid = t >> 6;
    if ((t & 63) == 0) {
        rbuf[0][wid] = a0; rbuf[1][wid] = a1; rbuf[2][wid] = a2;
        rbuf[3][wid] = a3; rbuf[4][wid] = a4;
    }
    __syncthreads();
    if (t == 0) {
        float n[5];
        for (int k = 0; k < 5; ++k) {
            float s = 0.f;
            for (int w = 0; w < 6; ++w) s += rbuf[k][w];
            n[k] = s;
        }
        int cells[5] = { sx * NL + sy, lxm * NL + sy, lxp * NL + sy,
                         sx * NL + lym, sx * NL + lyp };
        float l[5];
        for (int k = 0; k < 5; ++k) {
            float ls  = ws[LOCALSUM + b * (NL * NL) + cells[k]];
            float lsq = ws[LOCALSQ  + b * (NL * NL) + cells[k]];
            float ivar = lsq - ls * ls * (1.0f / N_T) + EPSF;
            if (ivar < 0.f) ivar = 0.f;
            float ncc = n[k] / sqrtf(tvar * ivar);
            if (ncc != ncc) ncc = 0.f;
            l[k] = logf(ncc);
        }
        float shx = -(float)(sx - 10) - (l[1] - l[2]) / (2.f * l[1] - 4.f * l[0] + 2.f * l[2]);
        float shy = -(float)(sy - 10) - (l[3] - l[4]) / (2.f * l[3] - 4.f * l[0] + 2.f * l[4]);
        ws[SHIFTS + 2 * b]     = shx;
        ws[SHIFTS + 2 * b + 1] = shy;
    }
}

// ---------------- K5: bilinear warp, LDS-tiled (weights are const per batch) ----------------
__global__ __launch_bounds__(256) void k_warp(const float* __restrict__ x,
                                              const float* __restrict__ ws,
                                              float* __restrict__ out) {
    const int b = blockIdx.z;
    const int R = blockIdx.x * 64;     // output row tile
    const int C = blockIdx.y * 64;     // output col tile
    const float dy = ws[SHIFTS + 2 * b], dx = ws[SHIFTS + 2 * b + 1];
    const int rlo = (int)floorf((float)R - dy);
    const int clo = (int)floorf((float)C - dx);
    const float wr = ((float)R - dy) - (float)rlo;
    const float wc = ((float)C - dx) - (float)clo;
    __shared__ float sm[66][67];       // 66x66 staged tile, stride 67 (2-way free)
    const float* img = x + (size_t)b * (HH * WW);

    for (int k = threadIdx.x; k < 66 * 66; k += 256) {
        int kr = k / 66, kc = k - kr * 66;
        int ri = min(max(rlo + kr, 0), HH - 1);
        int ci = min(max(clo + kc, 0), WW - 1);
        sm[kr][kc] = img[ri * WW + ci];
    }
    __syncthreads();

    const int dr = threadIdx.x & 63;
    const int cq = threadIdx.x >> 6;     // 0..3
    const int r  = R + dr;
    const int r0 = rlo + dr;
    const float w00 = (1.f - wr) * (1.f - wc), w01 = (1.f - wr) * wc;
    const float w10 = wr * (1.f - wc),         w11 = wr * wc;
    const bool vr0 = (r0 >= 0) & (r0 < HH);
    const bool vr1 = (r0 + 1 >= 0) & (r0 + 1 < HH);
#pragma unroll
    for (int ci = 0; ci < 16; ++ci) {
        int dc = cq * 16 + ci;
        int c  = C + dc;
        int c0 = clo + dc;
        bool vc0 = (c0 >= 0) & (c0 < WW);
        bool vc1 = (c0 + 1 >= 0) & (c0 + 1 < WW);
        float v00 = (vr0 & vc0) ? sm[dr][dc]         : 0.f;
        float v01 = (vr0 & vc1) ? sm[dr][dc + 1]     : 0.f;
        float v10 = (vr1 & vc0) ? sm[dr + 1][dc]     : 0.f;
        float v11 = (vr1 & vc1) ? sm[dr + 1][dc + 1] : 0.f;
        float o = v00 * w00 + v01 * w01 + v10 * w10 + v11 * w11;
        out[(size_t)b * (HH * WW) + (size_t)c * HH + r] = o;
    }
}

extern "C" void kernel_launch(void* const* d_in, const int* in_sizes, int n_in,
                              void* d_out, int out_size, void* d_ws, size_t ws_size,
                              hipStream_t stream) {
    const float* x   = (const float*)d_in[0];
    const float* tpl = (const float*)d_in[1];
    float* out = (float*)d_out;
    float* ws  = (float*)d_ws;

    k_tstats1<<<TN, 128, 0, stream>>>(tpl, ws);
    k_tstats2<<<1, 512, 0, stream>>>(ws);
    k_rowsum<<<(NB * XN) / 4, 256, 0, stream>>>(x, ws);
    k_vert<<<NB, 512, 0, stream>>>(ws);
    k_cc<<<dim3(NB, 16), 256, 0, stream>>>(x, tpl, ws);
    k_ncc<<<NB, 512, 0, stream>>>(ws);
    k_exact<<<NB, 384, 0, stream>>>(x, tpl, ws);
    k_warp<<<dim3(8, 8, NB), dim3(256), 0, stream>>>(x, ws, out);
}

// Round 4
// 222.622 us; speedup vs baseline: 1.2312x; 1.2312x over previous
//
#include <hip/hip_runtime.h>
#include <math.h>

// Problem constants
#define HH 512
#define WW 512
#define NB 64
#define CXY 56          // crop offset of Xc in x
#define TOFF 66         // crop offset of tmpl in template (MS+C = 10+56)
#define TN 380          // template side
#define XN 400          // cropped image side
#define NL 21           // number of lags per dim (XN-TN+1)
#define N_T 144400.0f   // TN*TN
#define EPSF 1e-8f

// d_ws float offsets
#define TPART_S   0                    // 380
#define TPART_S2  384                  // 380
#define TSTATS    768                  // [0]=mu_t [1]=t_var
#define ROWSUM    1024                 // 64*400*21 = 537600
#define ROWSUMSQ  (ROWSUM + 537600)
#define LOCALSUM  (ROWSUMSQ + 537600)  // 64*441
#define LOCALSQ   (LOCALSUM + 28224)
#define CCPART    (LOCALSQ + 28224)    // 64*16*441 = 451584
#define SHIFTS    (CCPART + 451584)    // 128  (final float shifts)
#define SHIFTSI   (SHIFTS + 128)       // 128  (integer argmax cells)
#define EXACTN    (SHIFTSI + 128)      // 320  (exact numerators, 5 per batch)

typedef _Float16 half2_t __attribute__((ext_vector_type(2)));

#if defined(__has_builtin)
#if __has_builtin(__builtin_amdgcn_fdot2)
#define FDOT2(a, b, c) __builtin_amdgcn_fdot2((a), (b), (c), false)
#endif
#endif
#ifndef FDOT2
static __device__ inline float fdot2_asm(half2_t a, half2_t b, float c) {
    asm("v_dot2_f32_f16 %0, %1, %2, %0" : "+v"(c) : "v"(a), "v"(b));
    return c;
}
#define FDOT2(a, b, c) fdot2_asm((a), (b), (c))
#endif

static __device__ inline half2_t as_h2(float f) {
    return __builtin_bit_cast(half2_t, f);
}

// ---------------- K0a: per-template-row partial sums ----------------
__global__ __launch_bounds__(128) void k_tstats1(const float* __restrict__ tpl,
                                                 float* __restrict__ ws) {
    int u = blockIdx.x;            // 0..379
    int l = threadIdx.x;           // 128
    const float* row = tpl + (TOFF + u) * WW + TOFF;
    float s = 0.f, s2 = 0.f;
    for (int v = l; v < TN; v += 128) { float t = row[v]; s += t; s2 += t * t; }
    for (int off = 32; off; off >>= 1) { s += __shfl_down(s, off); s2 += __shfl_down(s2, off); }
    __shared__ float rs[2], rs2[2];
    int wid = l >> 6;
    if ((l & 63) == 0) { rs[wid] = s; rs2[wid] = s2; }
    __syncthreads();
    if (l == 0) { ws[TPART_S + u] = rs[0] + rs[1]; ws[TPART_S2 + u] = rs2[0] + rs2[1]; }
}

// ---------------- K0b: finalize template stats ----------------
__global__ __launch_bounds__(512) void k_tstats2(float* __restrict__ ws) {
    int l = threadIdx.x;           // 512
    float s  = (l < TN) ? ws[TPART_S + l]  : 0.f;
    float s2 = (l < TN) ? ws[TPART_S2 + l] : 0.f;
    for (int off = 32; off; off >>= 1) { s += __shfl_down(s, off); s2 += __shfl_down(s2, off); }
    __shared__ float rs[8], rs2[8];
    int wid = l >> 6;
    if ((l & 63) == 0) { rs[wid] = s; rs2[wid] = s2; }
    __syncthreads();
    if (l == 0) {
        float S = 0.f, S2 = 0.f;
        for (int k = 0; k < 8; ++k) { S += rs[k]; S2 += rs2[k]; }
        float mu = S / N_T;
        ws[TSTATS] = mu;
        ws[TSTATS + 1] = S2 - S * mu + EPSF;   // sum((T-mu)^2) + EPS
    }
}

// ---------------- K1: per-row 380-wide sliding window sums ----------------
__global__ __launch_bounds__(256) void k_rowsum(const float* __restrict__ x,
                                                float* __restrict__ ws) {
    __shared__ float sm[4][XN];
    int wid = threadIdx.x >> 6, lane = threadIdx.x & 63;
    int row = blockIdx.x * 4 + wid;        // 0..25599
    int b = row / XN, p = row % XN;
    const float* xr = x + ((size_t)b * HH + (CXY + p)) * WW + CXY;
    float s = 0.f, s2 = 0.f;
    for (int v = lane; v < XN; v += 64) {
        float t = xr[v];
        sm[wid][v] = t;
        if (v < TN) { s += t; s2 += t * t; }
    }
    for (int off = 32; off; off >>= 1) { s += __shfl_down(s, off); s2 += __shfl_down(s2, off); }
    __syncthreads();
    if (lane == 0) {
        float* rs  = ws + ROWSUM   + (size_t)row * NL;
        float* rq  = ws + ROWSUMSQ + (size_t)row * NL;
        float w = s, w2 = s2;
        rs[0] = w; rq[0] = w2;
        for (int j = 1; j < NL; ++j) {
            float a = sm[wid][j - 1], bv = sm[wid][j + TN - 1];
            w  += bv - a;
            w2 += bv * bv - a * a;
            rs[j] = w; rq[j] = w2;
        }
    }
}

// ---------------- K2: vertical 380-tall sums -> localsum / localsum_sq ----------------
__global__ __launch_bounds__(512) void k_vert(float* __restrict__ ws) {
    int b = blockIdx.x, t = threadIdx.x;
    __shared__ float sm[XN * NL];   // 8400 floats = 33.6KB
    for (int k = t; k < XN * NL; k += 512) sm[k] = ws[ROWSUM + (size_t)b * (XN * NL) + k];
    __syncthreads();
    if (t < NL * NL) {
        float s = 0.f;
        for (int p = 0; p < TN; ++p) s += sm[t + p * NL];
        ws[LOCALSUM + b * (NL * NL) + t] = s;
    }
    __syncthreads();
    for (int k = t; k < XN * NL; k += 512) sm[k] = ws[ROWSUMSQ + (size_t)b * (XN * NL) + k];
    __syncthreads();
    if (t < NL * NL) {
        float s = 0.f;
        for (int p = 0; p < TN; ++p) s += sm[t + p * NL];
        ws[LOCALSQ + b * (NL * NL) + t] = s;
    }
}

// ---------------- K3: f16 cross-correlation via v_dot2_f32_f16 ----------------
#define RPB 25           // X rows per block (16 blocks/batch)
#define TSH 388          // halfs per T row in LDS (194 floats; 776 B row stride)
__global__ __launch_bounds__(256) void k_cc(const float* __restrict__ x,
                                            const float* __restrict__ tpl,
                                            float* __restrict__ ws) {
    __shared__ __align__(16) float sThF[21 * 194];   // 21 T rows as f16
    __shared__ __align__(16) float sXaF[208];        // 416 halfs
    __shared__ __align__(16) float sXbF[208];        // 416 halfs (shifted by 1)
    _Float16* sTh = (_Float16*)sThF;
    _Float16* sXa = (_Float16*)sXaF;
    _Float16* sXb = (_Float16*)sXbF;
    const int b = blockIdx.x, s = blockIdx.y;
    const int p0 = s * RPB;
    const int tid = threadIdx.x;
    const float mu = ws[TSTATS];

    // initial ring: T rows u in [p0-20, p0-1]
    for (int r = 0; r < 20; ++r) {
        int u = p0 - 20 + r;
        int slot = ((u % 21) + 21) % 21;
        _Float16* dst = sTh + slot * TSH;
        if (u >= 0) {
            const float* src = tpl + (TOFF + u) * WW + TOFF;
            for (int w = tid; w < TSH; w += 256) dst[w] = (_Float16)((w < TN) ? (src[w] - mu) : 0.f);
        } else {
            for (int w = tid; w < TSH; w += 256) dst[w] = (_Float16)0.f;
        }
    }

    const int i = tid % 21, c = tid / 21;   // lag-row, v-chunk(32); active if tid<252
    const bool act = (tid < 252);
    float acc[NL];
#pragma unroll
    for (int j = 0; j < NL; ++j) acc[j] = 0.f;

    // prefetch row p0 (raw f32; convert at LDS-write time)
    float tp0 = 0.f, tp1 = 0.f, xp0 = 0.f, xp1 = 0.f;
    {
        if (p0 < TN) {
            const float* src = tpl + (TOFF + p0) * WW + TOFF;
            tp0 = src[tid]; tp1 = src[tid + 256];    // in-bounds: TOFF+387 < 512
        }
        const float* xr = x + ((size_t)b * HH + (CXY + p0)) * WW + CXY;
        xp0 = xr[tid]; xp1 = xr[tid + 256];          // in-bounds: CXY+407 < 512
    }

    for (int p = p0; p < p0 + RPB; ++p) {
        __syncthreads();   // full drain: prev compute done + prefetch loads arrived
        if (p <= TN - 1) { // stage template row u=p into slot p%21
            _Float16* dst = sTh + (p % 21) * TSH;
            dst[tid] = (_Float16)(tp0 - mu);
            if (tid + 256 < TSH) dst[tid + 256] = (_Float16)((tid + 256 < TN) ? (tp1 - mu) : 0.f);
        }
        {   // stage X row p into sXa (aligned) and sXb (shift-1)
            float xa0 = (tid < XN) ? xp0 : 0.f;
            float xa1 = (tid + 256 < XN) ? xp1 : 0.f;
            _Float16 h0 = (_Float16)xa0, h1 = (_Float16)xa1;
            sXa[tid] = h0;
            if (tid + 256 < 416) sXa[tid + 256] = h1;
            if (tid >= 1) sXb[tid - 1] = h0;
            if (tid + 255 < 416) sXb[tid + 255] = h1;
        }
        // prefetch row p+1 (overlaps compute; not drained at the raw barrier)
        {
            int pn = p + 1;
            if (pn < TN) {
                const float* src = tpl + (TOFF + pn) * WW + TOFF;
                tp0 = src[tid]; tp1 = src[tid + 256];
            }
            if (pn < XN) {
                const float* xr = x + ((size_t)b * HH + (CXY + pn)) * WW + CXY;
                xp0 = xr[tid]; xp1 = xr[tid + 256];
            }
        }
        // raw barrier: waits LDS writes only; prefetch vmem stays in flight
        asm volatile("s_waitcnt lgkmcnt(0)\n\ts_barrier" ::: "memory");

        int u = p - i;
        if (act && u <= TN - 1) {           // u<0 slots are zero-filled: contribute 0
            int slot = ((u % 21) + 21) % 21;
            // T chunk: 32 halfs = 16 half2, via 8 x ds_read_b64
            const float2* trow = (const float2*)sThF + slot * 97 + c * 8;
            half2_t t2[16];
#pragma unroll
            for (int k = 0; k < 8; ++k) {
                float2 f2 = trow[k];
                t2[2 * k]     = as_h2(f2.x);
                t2[2 * k + 1] = as_h2(f2.y);
            }
            // X windows: 28 half2 each from sXa/sXb via 7 x ds_read_b128
            const float4* wa4 = (const float4*)sXaF + 4 * c;
            const float4* wb4 = (const float4*)sXbF + 4 * c;
            half2_t wA[28], wB[28];
#pragma unroll
            for (int q = 0; q < 7; ++q) {
                float4 va = wa4[q];
                wA[4 * q]     = as_h2(va.x); wA[4 * q + 1] = as_h2(va.y);
                wA[4 * q + 2] = as_h2(va.z); wA[4 * q + 3] = as_h2(va.w);
                float4 vb = wb4[q];
                wB[4 * q]     = as_h2(vb.x); wB[4 * q + 1] = as_h2(vb.y);
                wB[4 * q + 2] = as_h2(vb.z); wB[4 * q + 3] = as_h2(vb.w);
            }
#pragma unroll
            for (int v2 = 0; v2 < 16; ++v2) {
                half2_t t = t2[v2];
#pragma unroll
                for (int j = 0; j < NL; ++j) {
                    half2_t xp = (j & 1) ? wB[v2 + ((j - 1) >> 1)] : wA[v2 + (j >> 1)];
                    acc[j] = FDOT2(xp, t, acc[j]);
                }
            }
        }
    }

    // two-pass deterministic reduction over c-chunks (reuse sThF: need 2772 floats)
    float* red = sThF;
    __syncthreads();
    if (act && i < 11) {
#pragma unroll
        for (int j = 0; j < NL; ++j) red[(i * NL + j) * 12 + c] = acc[j];
    }
    __syncthreads();
    if (tid < 231) {
        float ssum = 0.f;
#pragma unroll
        for (int cc2 = 0; cc2 < 12; ++cc2) ssum += red[tid * 12 + cc2];
        ws[CCPART + ((size_t)(b * 16 + s)) * (NL * NL) + tid] = ssum;
    }
    __syncthreads();
    if (act && i >= 11) {
#pragma unroll
        for (int j = 0; j < NL; ++j) red[((i - 11) * NL + j) * 12 + c] = acc[j];
    }
    __syncthreads();
    if (tid < 210) {
        float ssum = 0.f;
#pragma unroll
        for (int cc2 = 0; cc2 < 12; ++cc2) ssum += red[tid * 12 + cc2];
        ws[CCPART + ((size_t)(b * 16 + s)) * (NL * NL) + 231 + tid] = ssum;
    }
}

// ---------------- K4: NCC + argmax (first-index ties) -> integer cell ----------------
__global__ __launch_bounds__(512) void k_ncc(float* __restrict__ ws) {
    int b = blockIdx.x, t = threadIdx.x;
    __shared__ float vbuf[512];
    __shared__ int   ibuf[512];
    float val = -1e30f;
    if (t < NL * NL) {
        float num = 0.f;
        for (int sl = 0; sl < 16; ++sl)
            num += ws[CCPART + ((size_t)(b * 16 + sl)) * (NL * NL) + t];
        float ls  = ws[LOCALSUM + b * (NL * NL) + t];
        float lsq = ws[LOCALSQ  + b * (NL * NL) + t];
        float ivar = lsq - ls * ls * (1.0f / N_T) + EPSF;
        if (ivar < 0.f) ivar = 0.f;
        float den = sqrtf(ws[TSTATS + 1] * ivar);
        float ncc = num / den;
        if (ncc != ncc) ncc = 0.f;
        val = ncc;
    }
    vbuf[t] = val; ibuf[t] = t;
    __syncthreads();
    for (int off = 256; off; off >>= 1) {
        if (t < off) {
            float v1 = vbuf[t], v2 = vbuf[t + off];
            int   i1 = ibuf[t], i2 = ibuf[t + off];
            if (v2 > v1 || (v2 == v1 && i2 < i1)) { vbuf[t] = v2; ibuf[t] = i2; }
        }
        __syncthreads();
    }
    if (t == 0) {
        int am = ibuf[0];
        ws[SHIFTSI + 2 * b]     = (float)(am / NL);
        ws[SHIFTSI + 2 * b + 1] = (float)(am % NL);
    }
}

// ---------------- K4b: exact fp32 numerators at the 5 stencil points ----------------
// grid (NB, 5), 256 threads; wave-per-row-group, lane-coalesced column reads.
__global__ __launch_bounds__(256) void k_exact1(const float* __restrict__ x,
                                                const float* __restrict__ tpl,
                                                float* __restrict__ ws) {
    const int b = blockIdx.x, k = blockIdx.y;
    const int sx = (int)ws[SHIFTSI + 2 * b];
    const int sy = (int)ws[SHIFTSI + 2 * b + 1];
    const int dxs[5] = {0, -1, 1, 0, 0};
    const int dys[5] = {0, 0, 0, -1, 1};
    const int px = min(max(sx + dxs[k], 0), NL - 1);
    const int py = min(max(sy + dys[k], 0), NL - 1);
    const float mu = ws[TSTATS];
    const int lane = threadIdx.x & 63, wv = threadIdx.x >> 6;
    float a = 0.f;
    for (int t = wv; t < TN; t += 4) {
        const float* trow = tpl + (TOFF + t) * WW + TOFF;
        const float* xrow = x + ((size_t)b * HH + (CXY + px + t)) * WW + CXY + py;
#pragma unroll
        for (int it = 0; it < 6; ++it) {
            int v = lane + it * 64;
            if (v < TN) a = fmaf(trow[v] - mu, xrow[v], a);
        }
    }
    for (int off = 32; off; off >>= 1) a += __shfl_down(a, off);
    __shared__ float part[4];
    if (lane == 0) part[wv] = a;
    __syncthreads();
    if (threadIdx.x == 0)
        ws[EXACTN + b * 5 + k] = part[0] + part[1] + part[2] + part[3];
}

// ---------------- K4c: subpixel shifts from exact numerators ----------------
__global__ __launch_bounds__(64) void k_sub(float* __restrict__ ws) {
    int b = threadIdx.x;
    if (b >= NB) return;
    int sx = (int)ws[SHIFTSI + 2 * b];
    int sy = (int)ws[SHIFTSI + 2 * b + 1];
    int lxm = max(sx - 1, 0), lxp = min(sx + 1, NL - 1);
    int lym = max(sy - 1, 0), lyp = min(sy + 1, NL - 1);
    float tvar = ws[TSTATS + 1];
    int cells[5] = { sx * NL + sy, lxm * NL + sy, lxp * NL + sy,
                     sx * NL + lym, sx * NL + lyp };
    float l[5];
    for (int k = 0; k < 5; ++k) {
        float num = ws[EXACTN + b * 5 + k];
        float ls  = ws[LOCALSUM + b * (NL * NL) + cells[k]];
        float lsq = ws[LOCALSQ  + b * (NL * NL) + cells[k]];
        float ivar = lsq - ls * ls * (1.0f / N_T) + EPSF;
        if (ivar < 0.f) ivar = 0.f;
        float ncc = num / sqrtf(tvar * ivar);
        if (ncc != ncc) ncc = 0.f;
        l[k] = logf(ncc);
    }
    float shx = -(float)(sx - 10) - (l[1] - l[2]) / (2.f * l[1] - 4.f * l[0] + 2.f * l[2]);
    float shy = -(float)(sy - 10) - (l[3] - l[4]) / (2.f * l[3] - 4.f * l[0] + 2.f * l[4]);
    ws[SHIFTS + 2 * b]     = shx;
    ws[SHIFTS + 2 * b + 1] = shy;
}

// ---------------- K5: bilinear warp, LDS-tiled (weights are const per batch) ----------------
__global__ __launch_bounds__(256) void k_warp(const float* __restrict__ x,
                                              const float* __restrict__ ws,
                                              float* __restrict__ out) {
    const int b = blockIdx.z;
    const int R = blockIdx.x * 64;     // output row tile
    const int C = blockIdx.y * 64;     // output col tile
    const float dy = ws[SHIFTS + 2 * b], dx = ws[SHIFTS + 2 * b + 1];
    const int rlo = (int)floorf((float)R - dy);
    const int clo = (int)floorf((float)C - dx);
    const float wr = ((float)R - dy) - (float)rlo;
    const float wc = ((float)C - dx) - (float)clo;
    __shared__ float sm[66][67];       // 66x66 staged tile, stride 67 (2-way free)
    const float* img = x + (size_t)b * (HH * WW);

    for (int k = threadIdx.x; k < 66 * 66; k += 256) {
        int kr = k / 66, kc = k - kr * 66;
        int ri = min(max(rlo + kr, 0), HH - 1);
        int ci = min(max(clo + kc, 0), WW - 1);
        sm[kr][kc] = img[ri * WW + ci];
    }
    __syncthreads();

    const int dr = threadIdx.x & 63;
    const int cq = threadIdx.x >> 6;     // 0..3
    const int r  = R + dr;
    const int r0 = rlo + dr;
    const float w00 = (1.f - wr) * (1.f - wc), w01 = (1.f - wr) * wc;
    const float w10 = wr * (1.f - wc),         w11 = wr * wc;
    const bool vr0 = (r0 >= 0) & (r0 < HH);
    const bool vr1 = (r0 + 1 >= 0) & (r0 + 1 < HH);
#pragma unroll
    for (int ci = 0; ci < 16; ++ci) {
        int dc = cq * 16 + ci;
        int c  = C + dc;
        int c0 = clo + dc;
        bool vc0 = (c0 >= 0) & (c0 < WW);
        bool vc1 = (c0 + 1 >= 0) & (c0 + 1 < WW);
        float v00 = (vr0 & vc0) ? sm[dr][dc]         : 0.f;
        float v01 = (vr0 & vc1) ? sm[dr][dc + 1]     : 0.f;
        float v10 = (vr1 & vc0) ? sm[dr + 1][dc]     : 0.f;
        float v11 = (vr1 & vc1) ? sm[dr + 1][dc + 1] : 0.f;
        float o = v00 * w00 + v01 * w01 + v10 * w10 + v11 * w11;
        out[(size_t)b * (HH * WW) + (size_t)c * HH + r] = o;
    }
}

extern "C" void kernel_launch(void* const* d_in, const int* in_sizes, int n_in,
                              void* d_out, int out_size, void* d_ws, size_t ws_size,
                              hipStream_t stream) {
    const float* x   = (const float*)d_in[0];
    const float* tpl = (const float*)d_in[1];
    float* out = (float*)d_out;
    float* ws  = (float*)d_ws;

    k_tstats1<<<TN, 128, 0, stream>>>(tpl, ws);
    k_tstats2<<<1, 512, 0, stream>>>(ws);
    k_rowsum<<<(NB * XN) / 4, 256, 0, stream>>>(x, ws);
    k_vert<<<NB, 512, 0, stream>>>(ws);
    k_cc<<<dim3(NB, 16), 256, 0, stream>>>(x, tpl, ws);
    k_ncc<<<NB, 512, 0, stream>>>(ws);
    k_exact1<<<dim3(NB, 5), 256, 0, stream>>>(x, tpl, ws);
    k_sub<<<1, 64, 0, stream>>>(ws);
    k_warp<<<dim3(8, 8, NB), dim3(256), 0, stream>>>(x, ws, out);
}